// Round 7
// baseline (273.512 us; speedup 1.0000x reference)
//
#include <hip/hip_runtime.h>
#include <hip/hip_bf16.h>
#include <math.h>

// Problem dims (fixed by setup_inputs)
#define E_   8
#define H_   768
#define I_   3072
#define T_   2048
#define NTOK (E_ * T_)

typedef __attribute__((ext_vector_type(8))) short bf16x8;   // 8 bf16 = 4 VGPRs
typedef __attribute__((ext_vector_type(4))) float f32x4;    // MFMA accum

typedef __attribute__((address_space(3))) void lds_void;
typedef const __attribute__((address_space(1))) void gl_void;

__device__ __forceinline__ void gload16(const void* g, void* l) {
  // 16B async global->LDS. LDS dest is wave-uniform base + lane*16.
  __builtin_amdgcn_global_load_lds((gl_void*)g, (lds_void*)l, 16, 0, 0);
}

// Compiler-only fence (0 instructions) + raw HW barrier. NOT __syncthreads():
// that would emit s_waitcnt vmcnt(0) and drain the prefetch pipeline (T4).
#define FENCE() asm volatile("" ::: "memory")
#define BAR()                         \
  do {                                \
    FENCE();                          \
    __builtin_amdgcn_s_barrier();     \
    FENCE();                          \
  } while (0)
#define VMWAIT(n) asm volatile("s_waitcnt vmcnt(" #n ")" ::: "memory")
// lgkmcnt(0) + sched_barrier(0): pin ordering after the LDS drain
// (rule 18: hipcc can hoist reg-only MFMA past inline-asm lgkmcnt).
#define LGKM0()                                  \
  do {                                           \
    asm volatile("s_waitcnt lgkmcnt(0)" ::: "memory"); \
    __builtin_amdgcn_sched_barrier(0);           \
  } while (0)

#define MFMA16(a, b, c) __builtin_amdgcn_mfma_f32_16x16x32_bf16(a, b, c, 0, 0, 0)

// Fast GELU: v * sigmoid(1.5957691*(v + 0.044715 v^3)); |err| ~3e-4 << bf16
// storage error of the intermediate. (Round-2 verified, absmax 0.031.)
__device__ __forceinline__ float gelu_fast(float v) {
  float inner = v * fmaf(v * v, 0.044715f, 1.0f);
  float e = __builtin_amdgcn_exp2f(inner * -2.3022082f);
  return v * __builtin_amdgcn_rcpf(1.0f + e);
}

// ---------------------------------------------------------------------------
// fp32 -> bf16 elementwise convert
// ---------------------------------------------------------------------------
__global__ __launch_bounds__(256) void cvt_bf16_kernel(
    const float* __restrict__ in, __hip_bfloat16* __restrict__ out) {
  int i = (blockIdx.x * 256 + threadIdx.x) * 4;
  float4 v = *(const float4*)(in + i);
  __align__(8) __hip_bfloat16 t[4];
  t[0] = __float2bfloat16(v.x);
  t[1] = __float2bfloat16(v.y);
  t[2] = __float2bfloat16(v.z);
  t[3] = __float2bfloat16(v.w);
  *(ushort4*)(out + i) = *(const ushort4*)t;
}

// ---------------------------------------------------------------------------
// [E][R][C] fp32 -> [E][C][R] bf16 (64x64 LDS tiles; ushort2 stores)
// ---------------------------------------------------------------------------
__global__ __launch_bounds__(256) void transpose_cvt_kernel(
    const float* __restrict__ src, __hip_bfloat16* __restrict__ dst,
    int R, int C) {
  __shared__ __hip_bfloat16 tile[64][65];
  int e  = blockIdx.z;
  int c0 = blockIdx.x * 64;
  int r0 = blockIdx.y * 64;
  const float* s = src + (size_t)e * R * C;
  __hip_bfloat16* d = dst + (size_t)e * R * C;
  int tx = threadIdx.x & 63, ty = threadIdx.x >> 6;
#pragma unroll
  for (int r = ty; r < 64; r += 4)
    tile[r][tx] = __float2bfloat16(s[(size_t)(r0 + r) * C + c0 + tx]);
  __syncthreads();
  // Vectorized write: lane handles 2 consecutive output cols (ushort2 = 4B).
  int tx2 = threadIdx.x & 31;
  int ty2 = threadIdx.x >> 5;
#pragma unroll
  for (int rr = ty2; rr < 64; rr += 8) {
    ushort2 v;
    v.x = *(const ushort*)&tile[2 * tx2][rr];
    v.y = *(const ushort*)&tile[2 * tx2 + 1][rr];
    *(ushort2*)&d[(size_t)(c0 + rr) * R + r0 + 2 * tx2] = v;
  }
}

// ---------------------------------------------------------------------------
// Grouped GEMM, round-7: 128x128 tile, BK=64, 4 waves (2x2), per-wave 64x64
// out, mfma_f32_16x16x32_bf16. Double-buffered 64 KiB LDS ->
// __launch_bounds__(256,2) = 2 BLOCKS/CU. Rounds 3-6 showed all in-block
// schedules plateau at ~30-34% MfmaUtil with 1 block/CU (2 waves/SIMD,
// barrier-locked: read windows and MFMA windows alternate). Fix = cross-
// BLOCK overlap (m114): two independent blocks per CU fill each other's
// bubbles. Tile idiom confirmed by m103: 128² beats 256² for simple
// 2-barrier loops. Counted-vmcnt ledger (8 loads/tile, dbuf):
//   prologue: stage(buf0,t0), stage(buf1,t1)      -> 16 outstanding
//   tile t:   VMWAIT(8) [lands tile t; last tile VMWAIT(0)]
//             BAR; 16 ds_reads(buf p); LGKM0; BAR  [all readers drained]
//             stage(buf p, t+2) if exists           [WAR-safe after BAR]
//             32 MFMA; p ^= 1
// Never vmcnt(0) mid-loop; stage of t+2 has ~2 K-tiles of latency slack.
//
// T2 swizzle: LDS linear (gload_lds), global source col-group pre-swizzled
// cg = c8 ^ (lr&7); reads XOR the same (bank conflicts measured 0, round 3).
// T1 XCD swizzle: both grids are multiples of 8.
// ---------------------------------------------------------------------------
template <int K, int N, bool GELU>
__global__ __launch_bounds__(256, 2) void gemm128_kernel(
    const __hip_bfloat16* __restrict__ A,
    const __hip_bfloat16* __restrict__ B,
    const float* __restrict__ bias,
    __hip_bfloat16* __restrict__ out) {
  constexpr int MT = T_ / 128;
  constexpr int NT = N / 128;
  constexpr int KT = K / 64;
  static_assert(KT >= 2, "need >=2 K-tiles");

  __shared__ __hip_bfloat16 sA[2][128][64];
  __shared__ __hip_bfloat16 sB[2][128][64];

  // T1: bijective XCD swizzle (gridDim.x % 8 == 0 for both GEMMs).
  int nwg = gridDim.x;
  int b0  = blockIdx.x;
  int bid = (b0 & 7) * (nwg >> 3) + (b0 >> 3);

  int e   = bid / (MT * NT);
  int rr_ = bid % (MT * NT);
  int bm  = rr_ / NT;
  int bn  = rr_ % NT;

  const __hip_bfloat16* Ae = A + (size_t)e * T_ * K + (size_t)bm * 128 * K;
  const __hip_bfloat16* Be = B + (size_t)e * N  * K + (size_t)bn * 128 * K;

  int tid  = threadIdx.x;
  int lane = tid & 63;
  int wid  = tid >> 6;
  int wm   = wid >> 1, wn = wid & 1;  // 2x2 wave grid
  int l15  = lane & 15;
  int l16h = lane >> 4;  // 0..3

  // --- staging: 4 passes per operand; idx = q*256+tid; lr = idx>>3 (row),
  // c8 = idx&7 (16B col-group). T2: global col-group pre-swizzled.
  auto stage = [&](int buf, int kt) {
    const __hip_bfloat16* gA = Ae + (size_t)kt * 64;
    const __hip_bfloat16* gB = Be + (size_t)kt * 64;
#pragma unroll
    for (int q = 0; q < 4; ++q) {
      int idx = q * 256 + tid;
      int lr = idx >> 3, c8 = idx & 7;
      int cg = c8 ^ (lr & 7);
      gload16(gA + (size_t)lr * K + cg * 8, &sA[buf][lr][c8 * 8]);
    }
#pragma unroll
    for (int q = 0; q < 4; ++q) {
      int idx = q * 256 + tid;
      int lr = idx >> 3, c8 = idx & 7;
      int cg = c8 ^ (lr & 7);
      gload16(gB + (size_t)lr * K + cg * 8, &sB[buf][lr][c8 * 8]);
    }
  };

  // --- fragment-read geometry (T2 read-side XOR; row&7 == l15&7 for all
  // frag rows since wave/frag offsets are multiples of 16)
  int laBase = wm * 64 + l15;  // + mf*16
  int lbBase = wn * 64 + l15;  // + nf*16
  int s7   = l15 & 7;
  int cgr0 = ((0 | l16h) ^ s7) * 8;  // ks=0 element offset
  int cgr1 = ((4 | l16h) ^ s7) * 8;  // ks=1

  f32x4 acc[4][4] = {};
  bf16x8 af[4][2], bfv[4][2];

  // ---- prologue: 2 tiles in flight
  stage(0, 0);
  stage(1, 1);

  int p = 0;
  for (int kt = 0; kt < KT; ++kt) {
    if (kt + 1 < KT) { VMWAIT(8); } else { VMWAIT(0); }  // lands tile kt
    BAR();
#pragma unroll
    for (int mf = 0; mf < 4; ++mf) {
      int la = laBase + mf * 16;
      af[mf][0] = *(const bf16x8*)&sA[p][la][cgr0];
      af[mf][1] = *(const bf16x8*)&sA[p][la][cgr1];
    }
#pragma unroll
    for (int nf = 0; nf < 4; ++nf) {
      int lb = lbBase + nf * 16;
      bfv[nf][0] = *(const bf16x8*)&sB[p][lb][cgr0];
      bfv[nf][1] = *(const bf16x8*)&sB[p][lb][cgr1];
    }
    LGKM0();   // my reads drained
    BAR();     // ALL waves' reads drained -> buf p reusable
    if (kt + 2 < KT) stage(p, kt + 2);
    __builtin_amdgcn_s_setprio(1);
#pragma unroll
    for (int mf = 0; mf < 4; ++mf)
#pragma unroll
      for (int nf = 0; nf < 4; ++nf) {
        acc[mf][nf] = MFMA16(af[mf][0], bfv[nf][0], acc[mf][nf]);
        acc[mf][nf] = MFMA16(af[mf][1], bfv[nf][1], acc[mf][nf]);
      }
    __builtin_amdgcn_s_setprio(0);
    p ^= 1;
  }

  // ---- epilogue: +bias, optional GELU, bf16 store.
  // C/D mapping (m89): col = lane&15, row = (lane>>4)*4 + r.
  const float* be = bias + (size_t)e * N + bn * 128;
  __hip_bfloat16* oe =
      out + (size_t)e * T_ * N + (size_t)(bm * 128) * N + bn * 128;
  int r4 = l16h * 4;
#pragma unroll
  for (int mf = 0; mf < 4; ++mf) {
#pragma unroll
    for (int nf = 0; nf < 4; ++nf) {
      int cc   = wn * 64 + nf * 16 + l15;
      float bv = be[cc];
#pragma unroll
      for (int r = 0; r < 4; ++r) {
        int row = wm * 64 + mf * 16 + r4 + r;
        float v = acc[mf][nf][r] + bv;
        if (GELU) v = gelu_fast(v);
        oe[(size_t)row * N + cc] = __float2bfloat16(v);
      }
    }
  }
}

// ---------------------------------------------------------------------------
// Residual + LayerNorm: one 256-thread block per token row (H=768 = 3*256).
// ---------------------------------------------------------------------------
__global__ __launch_bounds__(256) void ln_kernel(
    const __hip_bfloat16* __restrict__ yraw, const float* __restrict__ x,
    const float* __restrict__ gamma, const float* __restrict__ beta,
    float* __restrict__ out) {
  int row  = blockIdx.x;
  int tid  = threadIdx.x;
  int lane = tid & 63, wid = tid >> 6;
  const __hip_bfloat16* yr = yraw + (size_t)row * H_;
  const float* xr = x + (size_t)row * H_;

  float v[3];
  float s = 0.f, s2 = 0.f;
#pragma unroll
  for (int j = 0; j < 3; ++j) {
    int c   = tid + j * 256;
    float t = __bfloat162float(yr[c]) + xr[c];
    v[j] = t;
    s += t;
    s2 += t * t;
  }
#pragma unroll
  for (int o = 32; o > 0; o >>= 1) {
    s  += __shfl_down(s, o);
    s2 += __shfl_down(s2, o);
  }
  __shared__ float ls[4], ls2[4];
  if (lane == 0) { ls[wid] = s; ls2[wid] = s2; }
  __syncthreads();
  float tot  = ls[0] + ls[1] + ls[2] + ls[3];
  float tot2 = ls2[0] + ls2[1] + ls2[2] + ls2[3];
  float mean = tot * (1.0f / 768.0f);
  float var  = tot2 * (1.0f / 768.0f) - mean * mean;
  float inv  = rsqrtf(var + 1e-12f);
  float* orow = out + (size_t)row * H_;
#pragma unroll
  for (int j = 0; j < 3; ++j) {
    int c = tid + j * 256;
    orow[c] = (v[j] - mean) * inv * gamma[c] + beta[c];
  }
}

// ---------------------------------------------------------------------------
extern "C" void kernel_launch(void* const* d_in, const int* in_sizes, int n_in,
                              void* d_out, int out_size, void* d_ws,
                              size_t ws_size, hipStream_t stream) {
  const float* x     = (const float*)d_in[0];  // [N, H]
  const float* w1    = (const float*)d_in[1];  // [E, H, I]
  const float* b1    = (const float*)d_in[2];  // [E, I]
  const float* w2    = (const float*)d_in[3];  // [E, I, H]
  const float* b2    = (const float*)d_in[4];  // [E, H]
  const float* gamma = (const float*)d_in[5];  // [H]
  const float* beta  = (const float*)d_in[6];  // [H]
  float* out = (float*)d_out;

  // Workspace layout (192 MiB):
  //   w1t  [E][I][H] bf16 @ 0           (37,748,736 B)
  //   w2t  [E][H][I] bf16 @ 37748736    (37,748,736 B)
  //   x_bf [N][H]    bf16 @ 75497472    (25,165,824 B; aliased by yraw)
  //   inter[E][T][I] bf16 @ 100663296   (100,663,296 B)
  char* ws = (char*)d_ws;
  __hip_bfloat16* w1t   = (__hip_bfloat16*)(ws);
  __hip_bfloat16* w2t   = (__hip_bfloat16*)(ws + 37748736);
  __hip_bfloat16* x_bf  = (__hip_bfloat16*)(ws + 75497472);
  __hip_bfloat16* inter = (__hip_bfloat16*)(ws + 100663296);
  __hip_bfloat16* yraw  = x_bf;  // x_bf dead after GEMM1; safe alias

  cvt_bf16_kernel<<<(NTOK * H_) / (256 * 4), 256, 0, stream>>>(x, x_bf);
  transpose_cvt_kernel<<<dim3(I_ / 64, H_ / 64, E_), 256, 0, stream>>>(
      w1, w1t, H_, I_);
  transpose_cvt_kernel<<<dim3(H_ / 64, I_ / 64, E_), 256, 0, stream>>>(
      w2, w2t, I_, H_);
  // GEMM1 + bias + GELU -> inter : 8*16*24 = 3072 blocks (6 rounds @ 2/CU)
  gemm128_kernel<H_, I_, true>
      <<<E_ * (T_ / 128) * (I_ / 128), 256, 0, stream>>>(x_bf, w1t, b1, inter);
  // GEMM2 + bias -> yraw : 8*16*6 = 768 blocks (1.5 rounds @ 2/CU)
  gemm128_kernel<I_, H_, false>
      <<<E_ * (T_ / 128) * (H_ / 128), 256, 0, stream>>>(inter, w2t, b2, yraw);
  ln_kernel<<<NTOK, 256, 0, stream>>>(yraw, x, gamma, beta, out);
}

// Round 8
// 242.077 us; speedup vs baseline: 1.1299x; 1.1299x over previous
//
#include <hip/hip_runtime.h>
#include <hip/hip_bf16.h>
#include <math.h>

// Problem dims (fixed by setup_inputs)
#define E_   8
#define H_   768
#define I_   3072
#define T_   2048
#define NTOK (E_ * T_)

typedef __attribute__((ext_vector_type(8))) short bf16x8;   // 8 bf16 = 4 VGPRs
typedef __attribute__((ext_vector_type(4))) float f32x4;    // MFMA accum

typedef __attribute__((address_space(3))) void lds_void;
typedef const __attribute__((address_space(1))) void gl_void;

__device__ __forceinline__ void gload16(const void* g, void* l) {
  // 16B async global->LDS. LDS dest is wave-uniform base + lane*16.
  __builtin_amdgcn_global_load_lds((gl_void*)g, (lds_void*)l, 16, 0, 0);
}

// Compiler-only fence (0 instructions) + raw HW barrier. NOT __syncthreads():
// that would emit s_waitcnt vmcnt(0) and drain the prefetch pipeline (T4).
#define FENCE() asm volatile("" ::: "memory")
#define BAR()                         \
  do {                                \
    FENCE();                          \
    __builtin_amdgcn_s_barrier();     \
    FENCE();                          \
  } while (0)
#define VMWAIT(n) asm volatile("s_waitcnt vmcnt(" #n ")" ::: "memory")

#define MFMA16(a, b, c) __builtin_amdgcn_mfma_f32_16x16x32_bf16(a, b, c, 0, 0, 0)

// Fast GELU: v * sigmoid(1.5957691*(v + 0.044715 v^3)); |err| ~3e-4 << bf16
// storage error of the intermediate. (Round-2 verified, absmax 0.031.)
__device__ __forceinline__ float gelu_fast(float v) {
  float inner = v * fmaf(v * v, 0.044715f, 1.0f);
  float e = __builtin_amdgcn_exp2f(inner * -2.3022082f);
  return v * __builtin_amdgcn_rcpf(1.0f + e);
}

// ---------------------------------------------------------------------------
// fp32 -> bf16 elementwise convert (float4 in, ushort4 out per thread)
// ---------------------------------------------------------------------------
__global__ __launch_bounds__(256) void cvt_bf16_kernel(
    const float* __restrict__ in, __hip_bfloat16* __restrict__ out) {
  int i = (blockIdx.x * 256 + threadIdx.x) * 4;
  float4 v = *(const float4*)(in + i);
  __align__(8) __hip_bfloat16 t[4];
  t[0] = __float2bfloat16(v.x);
  t[1] = __float2bfloat16(v.y);
  t[2] = __float2bfloat16(v.z);
  t[3] = __float2bfloat16(v.w);
  *(ushort4*)(out + i) = *(const ushort4*)t;
}

// ---------------------------------------------------------------------------
// [E][R][C] fp32 -> [E][C][R] bf16. 64x64 LDS tile; float2 loads (8B/lane,
// G13), ushort2 LDS writes (66-pad: 2 rows/wave -> 2-way bank alias = free,
// m136), ushort2 stores.
// ---------------------------------------------------------------------------
__global__ __launch_bounds__(256) void transpose_cvt_kernel(
    const float* __restrict__ src, __hip_bfloat16* __restrict__ dst,
    int R, int C) {
  __shared__ __hip_bfloat16 tile[64][66];
  int e  = blockIdx.z;
  int c0 = blockIdx.x * 64;
  int r0 = blockIdx.y * 64;
  const float* s = src + (size_t)e * R * C;
  __hip_bfloat16* d = dst + (size_t)e * R * C;
  int tx = threadIdx.x & 31;   // col-pair index (2 cols/thread)
  int ty = threadIdx.x >> 5;   // 8 rows/pass
#pragma unroll
  for (int r = ty; r < 64; r += 8) {
    float2 v = *(const float2*)&s[(size_t)(r0 + r) * C + c0 + 2 * tx];
    __hip_bfloat16 b0 = __float2bfloat16(v.x);
    __hip_bfloat16 b1 = __float2bfloat16(v.y);
    ushort2 w;
    w.x = *(const ushort*)&b0;
    w.y = *(const ushort*)&b1;
    *(ushort2*)&tile[r][2 * tx] = w;
  }
  __syncthreads();
  // write transposed: lane handles 2 consecutive output cols (= tile rows)
#pragma unroll
  for (int rr = ty; rr < 64; rr += 8) {
    ushort2 v;
    v.x = *(const ushort*)&tile[2 * tx][rr];
    v.y = *(const ushort*)&tile[2 * tx + 1][rr];
    *(ushort2*)&d[(size_t)(c0 + rr) * R + r0 + 2 * tx] = v;
  }
}

// ---------------------------------------------------------------------------
// Grouped GEMM, 256xBN 2-phase merged schedule (round-5 best: 96us/GEMM,
// 33% MfmaUtil = ~95% of the m248 grouped-GEMM reference). BK=64, 512 thr =
// 8 waves (2M x 4N); per-wave 128 x BN/4 out, mfma_f32_16x16x32_bf16.
// Round-8 delta: staging address offsets hoisted out of the K-loop
// (precomputed per-lane size_t offsets; per-tile addressing = shl+add).
//
// LDS: sA[2 buf][2 half][128][64], sB[2 buf][BN][64] bf16.
// Ph0 consumes A-half0 + all B; Ph1 consumes A-half1.
// Stage order per tile kt (targets buf p^1, data kt+1), FIFO instr units:
//   Ph0: A0' (2) + B' (BN/64)   Ph1: A1' (2)
// Waits (consumer side, counted; never 0 mid-loop):
//   Ph0 entry: VMWAIT(2) lands A0,B of kt (1-tile slack).
//   Ph1 entry: VMWAIT(4+BN/64) lands A1 of kt.
//   Peeled last tile: VMWAIT(2) / VMWAIT(0).
// T2 swizzle: LDS linear (gload_lds), global source col-group pre-swizzled
// cg = c8 ^ (lr&7); reads XOR the same (bank conflicts measured 0).
// T1 XCD swizzle: both grids are multiples of 8.
// ---------------------------------------------------------------------------
template <int K, int N, int BN, bool GELU>
__global__ __launch_bounds__(512, 2) void gemm2p_kernel(
    const __hip_bfloat16* __restrict__ A,
    const __hip_bfloat16* __restrict__ B,
    const float* __restrict__ bias,
    __hip_bfloat16* __restrict__ out) {
  constexpr int MT = T_ / 256;
  constexpr int NT = N / BN;
  constexpr int KT = K / 64;
  constexpr int NF = BN / 64;     // B frags per wave (4 or 3)
  constexpr int WCW = BN / 4;     // per-wave col width (64 or 48)
  constexpr int BPASS = BN / 64;  // B stage passes (4 or 3)

  __shared__ __hip_bfloat16 sA[2][2][128][64];
  __shared__ __hip_bfloat16 sB[2][BN][64];

  // T1: bijective XCD swizzle (gridDim.x % 8 == 0 for both GEMMs).
  int nwg = gridDim.x;
  int b0  = blockIdx.x;
  int bid = (b0 & 7) * (nwg >> 3) + (b0 >> 3);

  int e   = bid / (MT * NT);
  int rr_ = bid % (MT * NT);
  int bm  = rr_ / NT;
  int bn  = rr_ % NT;

  const __hip_bfloat16* Ae = A + (size_t)e * T_ * K + (size_t)bm * 256 * K;
  const __hip_bfloat16* Be = B + (size_t)e * N  * K + (size_t)bn * BN * K;

  int tid  = threadIdx.x;
  int lane = tid & 63;
  int wid  = tid >> 6;
  int wr   = wid >> 2;   // 0..1 (M)
  int wc   = wid & 3;    // 0..3 (N)
  int l15  = lane & 15;
  int l16h = lane >> 4;  // 0..3

  // --- staging geometry, HOISTED (loop-invariant per-lane offsets).
  // idx = pass*512 + tid; lr = idx>>3 (row), c8 = idx&7 (16B col-group);
  // T2: global col-group pre-swizzled cg = c8 ^ (lr&7).
  int i0 = tid, i1 = 512 + tid;
  int lr0 = i0 >> 3, c80 = i0 & 7, cg0 = c80 ^ (lr0 & 7);
  int lr1 = i1 >> 3, c81 = i1 & 7, cg1 = c81 ^ (lr1 & 7);
  int rA0 = ((lr0 >> 6) << 7) | (lr0 & 63);  // + h*64
  int rA1 = ((lr1 >> 6) << 7) | (lr1 & 63);
  const size_t oA0 = (size_t)rA0 * K + cg0 * 8;   // + h*64*K
  const size_t oA1 = (size_t)rA1 * K + cg1 * 8;
  const size_t HOFF = (size_t)64 * K;
  size_t oB[BPASS];
  int    dB[BPASS];  // LDS element offsets within sB[buf]
#pragma unroll
  for (int q = 0; q < BPASS; ++q) {
    int idx = q * 512 + tid;
    int lr = idx >> 3, c8 = idx & 7;
    int cg = c8 ^ (lr & 7);
    oB[q] = (size_t)lr * K + cg * 8;
    dB[q] = lr * 64 + c8 * 8;
  }

  auto stageA = [&](int buf, int h, int kt) {
    const __hip_bfloat16* g = Ae + (size_t)kt * 64 + (size_t)h * HOFF;
    gload16(g + oA0, &sA[buf][h][lr0][c80 * 8]);
    gload16(g + oA1, &sA[buf][h][lr1][c81 * 8]);
  };
  auto stageB = [&](int buf, int kt) {
    const __hip_bfloat16* g = Be + (size_t)kt * 64;
    __hip_bfloat16* l = &sB[buf][0][0];
#pragma unroll
    for (int q = 0; q < BPASS; ++q) gload16(g + oB[q], l + dB[q]);
  };

  // --- fragment-read geometry (T2 read-side XOR)
  int laBase = wr * 64 + l15;   // + mf*16, within A-half
  int lbBase = wc * WCW + l15;  // + nf*16
  int s7   = l15 & 7;
  int cgr0 = ((0 | l16h) ^ s7) * 8;  // ks=0 element offset
  int cgr1 = ((4 | l16h) ^ s7) * 8;  // ks=1

  f32x4 acc[8][NF] = {};  // [mh*4+mf][nf]
  bf16x8 af[4][2], bfv[NF][2];

  // ---- prologue: stage tile 0 in FIFO order A0, B, A1.
  stageA(0, 0, 0);
  stageB(0, 0);
  stageA(0, 1, 0);

  auto ktile = [&](int kt, int p, bool pf) {
    // ======== Ph0: quadrants (0,*). Needs A0 + all B. ========
    VMWAIT(2);  // lands A0,B of kt (leaves A1's 2)
    BAR();
#pragma unroll
    for (int mf = 0; mf < 4; ++mf) {
      int la = laBase + mf * 16;
      af[mf][0] = *(const bf16x8*)&sA[p][0][la][cgr0];
      af[mf][1] = *(const bf16x8*)&sA[p][0][la][cgr1];
    }
#pragma unroll
    for (int nf = 0; nf < NF; ++nf) {
      int lb = lbBase + nf * 16;
      bfv[nf][0] = *(const bf16x8*)&sB[p][lb][cgr0];
      bfv[nf][1] = *(const bf16x8*)&sB[p][lb][cgr1];
    }
    if (pf) {
      stageA(p ^ 1, 0, kt + 1);
      stageB(p ^ 1, kt + 1);
    }
    __builtin_amdgcn_s_setprio(1);
#pragma unroll
    for (int mf = 0; mf < 4; ++mf)
#pragma unroll
      for (int nf = 0; nf < NF; ++nf) {
        acc[mf][nf] = MFMA16(af[mf][0], bfv[nf][0], acc[mf][nf]);
        acc[mf][nf] = MFMA16(af[mf][1], bfv[nf][1], acc[mf][nf]);
      }
    __builtin_amdgcn_s_setprio(0);
    // ======== Ph1: quadrants (1,*). Needs A1 (af overwrite). ========
    if (pf) {
      if constexpr (BN == 256) { VMWAIT(6); } else { VMWAIT(5); }  // lands A1
    } else {
      VMWAIT(0);
    }
    BAR();
#pragma unroll
    for (int mf = 0; mf < 4; ++mf) {
      int la = laBase + mf * 16;
      af[mf][0] = *(const bf16x8*)&sA[p][1][la][cgr0];
      af[mf][1] = *(const bf16x8*)&sA[p][1][la][cgr1];
    }
    if (pf) stageA(p ^ 1, 1, kt + 1);
    __builtin_amdgcn_s_setprio(1);
#pragma unroll
    for (int mf = 0; mf < 4; ++mf)
#pragma unroll
      for (int nf = 0; nf < NF; ++nf) {
        acc[4 + mf][nf] = MFMA16(af[mf][0], bfv[nf][0], acc[4 + mf][nf]);
        acc[4 + mf][nf] = MFMA16(af[mf][1], bfv[nf][1], acc[4 + mf][nf]);
      }
    __builtin_amdgcn_s_setprio(0);
  };

  int p = 0;
  for (int kt = 0; kt < KT - 1; ++kt) {
    ktile(kt, p, true);
    p ^= 1;
  }
  ktile(KT - 1, p, false);  // peeled: no prefetch; waits 2/0

  // ---- epilogue: +bias, optional GELU, bf16 store.
  // C/D mapping (m89): col = lane&15, row = (lane>>4)*4 + r.
  const float* be = bias + (size_t)e * N + bn * BN;
  __hip_bfloat16* oe =
      out + (size_t)e * T_ * N + (size_t)(bm * 256) * N + bn * BN;
  int r4 = l16h * 4;
#pragma unroll
  for (int mi = 0; mi < 8; ++mi) {
    int mh = mi >> 2, mf = mi & 3;
    int rowb = wr * 128 + mh * 64 + mf * 16 + r4;
#pragma unroll
    for (int nf = 0; nf < NF; ++nf) {
      int cc   = wc * WCW + nf * 16 + l15;
      float bv = be[cc];
#pragma unroll
      for (int r = 0; r < 4; ++r) {
        float v = acc[mi][nf][r] + bv;
        if (GELU) v = gelu_fast(v);
        oe[(size_t)(rowb + r) * N + cc] = __float2bfloat16(v);
      }
    }
  }
}

// ---------------------------------------------------------------------------
// Residual + LayerNorm, vectorized (G13): 384 thr/row, each thread owns 2
// cols -> ushort2 loads of yraw and x_bf (residual in bf16: adds <=0.02 abs
// err, margin 0.031 -> ~0.05 vs 0.104 threshold). float2 stores.
// ---------------------------------------------------------------------------
__global__ __launch_bounds__(384) void ln_kernel(
    const __hip_bfloat16* __restrict__ yraw,
    const __hip_bfloat16* __restrict__ xbf,
    const float* __restrict__ gamma, const float* __restrict__ beta,
    float* __restrict__ out) {
  int row  = blockIdx.x;
  int tid  = threadIdx.x;
  int lane = tid & 63, wid = tid >> 6;  // 6 waves
  int c    = tid * 2;
  const __hip_bfloat16* yr = yraw + (size_t)row * H_;
  const __hip_bfloat16* xr = xbf + (size_t)row * H_;

  ushort2 ya = *(const ushort2*)&yr[c];
  ushort2 xa = *(const ushort2*)&xr[c];
  __hip_bfloat16 t;
  float v0, v1;
  *(ushort*)&t = ya.x; v0 = __bfloat162float(t);
  *(ushort*)&t = xa.x; v0 += __bfloat162float(t);
  *(ushort*)&t = ya.y; v1 = __bfloat162float(t);
  *(ushort*)&t = xa.y; v1 += __bfloat162float(t);

  float s = v0 + v1, s2 = v0 * v0 + v1 * v1;
#pragma unroll
  for (int o = 32; o > 0; o >>= 1) {
    s  += __shfl_down(s, o);
    s2 += __shfl_down(s2, o);
  }
  __shared__ float ls[6], ls2[6];
  if (lane == 0) { ls[wid] = s; ls2[wid] = s2; }
  __syncthreads();
  float tot  = ls[0] + ls[1] + ls[2] + ls[3] + ls[4] + ls[5];
  float tot2 = ls2[0] + ls2[1] + ls2[2] + ls2[3] + ls2[4] + ls2[5];
  float mean = tot * (1.0f / 768.0f);
  float var  = tot2 * (1.0f / 768.0f) - mean * mean;
  float inv  = rsqrtf(var + 1e-12f);
  float2 g = *(const float2*)&gamma[c];
  float2 b = *(const float2*)&beta[c];
  float2 o2;
  o2.x = (v0 - mean) * inv * g.x + b.x;
  o2.y = (v1 - mean) * inv * g.y + b.y;
  *(float2*)&out[(size_t)row * H_ + c] = o2;
}

// ---------------------------------------------------------------------------
extern "C" void kernel_launch(void* const* d_in, const int* in_sizes, int n_in,
                              void* d_out, int out_size, void* d_ws,
                              size_t ws_size, hipStream_t stream) {
  const float* x     = (const float*)d_in[0];  // [N, H]
  const float* w1    = (const float*)d_in[1];  // [E, H, I]
  const float* b1    = (const float*)d_in[2];  // [E, I]
  const float* w2    = (const float*)d_in[3];  // [E, I, H]
  const float* b2    = (const float*)d_in[4];  // [E, H]
  const float* gamma = (const float*)d_in[5];  // [H]
  const float* beta  = (const float*)d_in[6];  // [H]
  float* out = (float*)d_out;

  // Workspace layout (192 MiB, exactly full):
  //   w1t  [E][I][H] bf16 @ 0           (37,748,736 B; DEAD after GEMM1 ->
  //                                      yraw [N][H] bf16 aliases @0)
  //   w2t  [E][H][I] bf16 @ 37748736    (37,748,736 B)
  //   x_bf [N][H]    bf16 @ 75497472    (25,165,824 B; live until LN)
  //   inter[E][T][I] bf16 @ 100663296   (100,663,296 B)
  char* ws = (char*)d_ws;
  __hip_bfloat16* w1t   = (__hip_bfloat16*)(ws);
  __hip_bfloat16* w2t   = (__hip_bfloat16*)(ws + 37748736);
  __hip_bfloat16* x_bf  = (__hip_bfloat16*)(ws + 75497472);
  __hip_bfloat16* inter = (__hip_bfloat16*)(ws + 100663296);
  __hip_bfloat16* yraw  = (__hip_bfloat16*)(ws);  // w1t dead after GEMM1

  cvt_bf16_kernel<<<(NTOK * H_) / (256 * 4), 256, 0, stream>>>(x, x_bf);
  transpose_cvt_kernel<<<dim3(I_ / 64, H_ / 64, E_), 256, 0, stream>>>(
      w1, w1t, H_, I_);
  transpose_cvt_kernel<<<dim3(H_ / 64, I_ / 64, E_), 256, 0, stream>>>(
      w2, w2t, I_, H_);
  // GEMM1 + bias + GELU -> inter : BN=256, 8*8*12 = 768 blocks
  gemm2p_kernel<H_, I_, 256, true>
      <<<E_ * (T_ / 256) * (I_ / 256), 512, 0, stream>>>(x_bf, w1t, b1, inter);
  // GEMM2 + bias -> yraw : BN=192, 8*8*4 = 256 blocks (1 full CU round)
  gemm2p_kernel<I_, H_, 192, false>
      <<<E_ * (T_ / 256) * (H_ / 192), 512, 0, stream>>>(inter, w2t, b2, yraw);
  // residual + LayerNorm -> out (fp32); residual read as bf16 (x_bf)
  ln_kernel<<<NTOK, 384, 0, stream>>>(yraw, x_bf, gamma, beta, out);
}

// Round 9
// 238.496 us; speedup vs baseline: 1.1468x; 1.0150x over previous
//
#include <hip/hip_runtime.h>
#include <hip/hip_bf16.h>
#include <math.h>

// Problem dims (fixed by setup_inputs)
#define E_   8
#define H_   768
#define I_   3072
#define T_   2048
#define NTOK (E_ * T_)

typedef __attribute__((ext_vector_type(8))) short bf16x8;   // 8 bf16 = 4 VGPRs
typedef __attribute__((ext_vector_type(4))) float f32x4;    // MFMA accum

typedef __attribute__((address_space(3))) void lds_void;
typedef const __attribute__((address_space(1))) void gl_void;

__device__ __forceinline__ void gload16(const void* g, void* l) {
  // 16B async global->LDS. LDS dest is wave-uniform base + lane*16.
  __builtin_amdgcn_global_load_lds((gl_void*)g, (lds_void*)l, 16, 0, 0);
}

// Compiler-only fence (0 instructions) + raw HW barrier. NOT __syncthreads():
// that would emit s_waitcnt vmcnt(0) and drain the prefetch pipeline (T4).
#define FENCE() asm volatile("" ::: "memory")
#define BAR()                         \
  do {                                \
    FENCE();                          \
    __builtin_amdgcn_s_barrier();     \
    FENCE();                          \
  } while (0)
#define VMWAIT(n) asm volatile("s_waitcnt vmcnt(" #n ")" ::: "memory")

#define MFMA16(a, b, c) __builtin_amdgcn_mfma_f32_16x16x32_bf16(a, b, c, 0, 0, 0)

// Fast GELU: v * sigmoid(1.5957691*(v + 0.044715 v^3)); |err| ~3e-4 << bf16
// storage error of the intermediate. (Round-2 verified, absmax 0.031.)
__device__ __forceinline__ float gelu_fast(float v) {
  float inner = v * fmaf(v * v, 0.044715f, 1.0f);
  float e = __builtin_amdgcn_exp2f(inner * -2.3022082f);
  return v * __builtin_amdgcn_rcpf(1.0f + e);
}

// ---------------------------------------------------------------------------
// Fused prep kernel (round-9): one launch does
//   blocks [0, 12288)        : x fp32 -> x_bf bf16 (float4 / ushort4)
//   blocks [12288, 16896)    : w1 [E][H][I] -> w1t [E][I][H] bf16
//   blocks [16896, 21504)    : w2 [E][I][H] -> w2t [E][H][I] bf16
// Saves 2 launch gaps + inter-kernel drain bubbles; all branches are
// wave-uniform (whole block takes one path). Transposes: 64x64 LDS tile,
// float2 loads (G13), ushort2 LDS writes (66-pad), ushort2 stores.
// ---------------------------------------------------------------------------
#define CVT_BLOCKS 12288         // NTOK*H / (256*4)
#define WT_BLOCKS  4608          // (I/64)*(H/64)*E = 48*12*8

__global__ __launch_bounds__(256) void prep_kernel(
    const float* __restrict__ x, __hip_bfloat16* __restrict__ x_bf,
    const float* __restrict__ w1, __hip_bfloat16* __restrict__ w1t,
    const float* __restrict__ w2, __hip_bfloat16* __restrict__ w2t) {
  __shared__ __hip_bfloat16 tile[64][66];
  int b = blockIdx.x;

  if (b < CVT_BLOCKS) {  // ---- cvt branch
    int i = (b * 256 + threadIdx.x) * 4;
    float4 v = *(const float4*)(x + i);
    __align__(8) __hip_bfloat16 t[4];
    t[0] = __float2bfloat16(v.x);
    t[1] = __float2bfloat16(v.y);
    t[2] = __float2bfloat16(v.z);
    t[3] = __float2bfloat16(v.w);
    *(ushort4*)(x_bf + i) = *(const ushort4*)t;
    return;
  }

  // ---- transpose branches: [E][R][C] fp32 -> [E][C][R] bf16
  const float* src;
  __hip_bfloat16* dst;
  int R, C, c0, r0;
  if (b < CVT_BLOCKS + WT_BLOCKS) {
    int t = b - CVT_BLOCKS;
    int e = t / 576, rem = t % 576;       // 576 = (I/64)*(H/64)
    R = H_; C = I_;                       // src w1 [H][I]
    c0 = (rem % 48) * 64;                 // over C = I (48 tiles)
    r0 = (rem / 48) * 64;                 // over R = H (12 tiles)
    src = w1 + (size_t)e * R * C;
    dst = w1t + (size_t)e * R * C;
  } else {
    int t = b - (CVT_BLOCKS + WT_BLOCKS);
    int e = t / 576, rem = t % 576;
    R = I_; C = H_;                       // src w2 [I][H]
    c0 = (rem % 12) * 64;                 // over C = H (12 tiles)
    r0 = (rem / 12) * 64;                 // over R = I (48 tiles)
    src = w2 + (size_t)e * R * C;
    dst = w2t + (size_t)e * R * C;
  }

  int tx = threadIdx.x & 31;  // col-pair index (2 cols/thread)
  int ty = threadIdx.x >> 5;  // 8 rows/pass
#pragma unroll
  for (int r = ty; r < 64; r += 8) {
    float2 v = *(const float2*)&src[(size_t)(r0 + r) * C + c0 + 2 * tx];
    __hip_bfloat16 b0 = __float2bfloat16(v.x);
    __hip_bfloat16 b1 = __float2bfloat16(v.y);
    ushort2 w;
    w.x = *(const ushort*)&b0;
    w.y = *(const ushort*)&b1;
    *(ushort2*)&tile[r][2 * tx] = w;
  }
  __syncthreads();
#pragma unroll
  for (int rr = ty; rr < 64; rr += 8) {
    ushort2 v;
    v.x = *(const ushort*)&tile[2 * tx][rr];
    v.y = *(const ushort*)&tile[2 * tx + 1][rr];
    *(ushort2*)&dst[(size_t)(c0 + rr) * R + r0 + 2 * tx] = v;
  }
}

// ---------------------------------------------------------------------------
// Grouped GEMM, 256xBN 2-phase merged schedule (round-5/8 best: ~96us/GEMM,
// 33% MfmaUtil ~= 95% of the m248 grouped-GEMM plain-HIP reference). BK=64,
// 512 thr = 8 waves (2M x 4N); per-wave 128 x BN/4 out (acc = 128 f32/lane
// in AGPRs -> ~252 unified regs/wave -> 2 waves/SIMD is the structural
// occupancy ceiling; all deeper schedules measured equal or worse, r3-r7).
//
// LDS: sA[2 buf][2 half][128][64], sB[2 buf][BN][64] bf16.
// Ph0 consumes A-half0 + all B; Ph1 consumes A-half1.
// Stage order per tile kt (targets buf p^1, data kt+1), FIFO instr units:
//   Ph0: A0' (2) + B' (BN/64)   Ph1: A1' (2)
// Waits (consumer side, counted; never 0 mid-loop):
//   Ph0 entry: VMWAIT(2) lands A0,B of kt (1-tile slack).
//   Ph1 entry: VMWAIT(4+BN/64) lands A1 of kt.
//   Peeled last tile: VMWAIT(2) / VMWAIT(0).
// T2 swizzle: LDS linear (gload_lds), global source col-group pre-swizzled
// cg = c8 ^ (lr&7); reads XOR the same (bank conflicts measured 0).
// T1 XCD swizzle: both grids are multiples of 8.
// ---------------------------------------------------------------------------
template <int K, int N, int BN, bool GELU>
__global__ __launch_bounds__(512, 2) void gemm2p_kernel(
    const __hip_bfloat16* __restrict__ A,
    const __hip_bfloat16* __restrict__ B,
    const float* __restrict__ bias,
    __hip_bfloat16* __restrict__ out) {
  constexpr int MT = T_ / 256;
  constexpr int NT = N / BN;
  constexpr int KT = K / 64;
  constexpr int NF = BN / 64;     // B frags per wave (4 or 3)
  constexpr int WCW = BN / 4;     // per-wave col width (64 or 48)
  constexpr int BPASS = BN / 64;  // B stage passes (4 or 3)

  __shared__ __hip_bfloat16 sA[2][2][128][64];
  __shared__ __hip_bfloat16 sB[2][BN][64];

  // T1: bijective XCD swizzle (gridDim.x % 8 == 0 for both GEMMs).
  int nwg = gridDim.x;
  int b0  = blockIdx.x;
  int bid = (b0 & 7) * (nwg >> 3) + (b0 >> 3);

  int e   = bid / (MT * NT);
  int rr_ = bid % (MT * NT);
  int bm  = rr_ / NT;
  int bn  = rr_ % NT;

  const __hip_bfloat16* Ae = A + (size_t)e * T_ * K + (size_t)bm * 256 * K;
  const __hip_bfloat16* Be = B + (size_t)e * N  * K + (size_t)bn * BN * K;

  int tid  = threadIdx.x;
  int lane = tid & 63;
  int wid  = tid >> 6;
  int wr   = wid >> 2;   // 0..1 (M)
  int wc   = wid & 3;    // 0..3 (N)
  int l15  = lane & 15;
  int l16h = lane >> 4;  // 0..3

  // --- staging geometry, hoisted (loop-invariant per-lane offsets).
  int i0 = tid, i1 = 512 + tid;
  int lr0 = i0 >> 3, c80 = i0 & 7, cg0 = c80 ^ (lr0 & 7);
  int lr1 = i1 >> 3, c81 = i1 & 7, cg1 = c81 ^ (lr1 & 7);
  int rA0 = ((lr0 >> 6) << 7) | (lr0 & 63);  // + h*64
  int rA1 = ((lr1 >> 6) << 7) | (lr1 & 63);
  const size_t oA0 = (size_t)rA0 * K + cg0 * 8;   // + h*64*K
  const size_t oA1 = (size_t)rA1 * K + cg1 * 8;
  const size_t HOFF = (size_t)64 * K;
  size_t oB[BPASS];
  int    dB[BPASS];  // LDS element offsets within sB[buf]
#pragma unroll
  for (int q = 0; q < BPASS; ++q) {
    int idx = q * 512 + tid;
    int lr = idx >> 3, c8 = idx & 7;
    int cg = c8 ^ (lr & 7);
    oB[q] = (size_t)lr * K + cg * 8;
    dB[q] = lr * 64 + c8 * 8;
  }

  auto stageA = [&](int buf, int h, int kt) {
    const __hip_bfloat16* g = Ae + (size_t)kt * 64 + (size_t)h * HOFF;
    gload16(g + oA0, &sA[buf][h][lr0][c80 * 8]);
    gload16(g + oA1, &sA[buf][h][lr1][c81 * 8]);
  };
  auto stageB = [&](int buf, int kt) {
    const __hip_bfloat16* g = Be + (size_t)kt * 64;
    __hip_bfloat16* l = &sB[buf][0][0];
#pragma unroll
    for (int q = 0; q < BPASS; ++q) gload16(g + oB[q], l + dB[q]);
  };

  // --- fragment-read geometry (T2 read-side XOR)
  int laBase = wr * 64 + l15;   // + mf*16, within A-half
  int lbBase = wc * WCW + l15;  // + nf*16
  int s7   = l15 & 7;
  int cgr0 = ((0 | l16h) ^ s7) * 8;  // ks=0 element offset
  int cgr1 = ((4 | l16h) ^ s7) * 8;  // ks=1

  f32x4 acc[8][NF] = {};  // [mh*4+mf][nf]
  bf16x8 af[4][2], bfv[NF][2];

  // ---- prologue: stage tile 0 in FIFO order A0, B, A1.
  stageA(0, 0, 0);
  stageB(0, 0);
  stageA(0, 1, 0);

  auto ktile = [&](int kt, int p, bool pf) {
    // ======== Ph0: quadrants (0,*). Needs A0 + all B. ========
    VMWAIT(2);  // lands A0,B of kt (leaves A1's 2)
    BAR();
#pragma unroll
    for (int mf = 0; mf < 4; ++mf) {
      int la = laBase + mf * 16;
      af[mf][0] = *(const bf16x8*)&sA[p][0][la][cgr0];
      af[mf][1] = *(const bf16x8*)&sA[p][0][la][cgr1];
    }
#pragma unroll
    for (int nf = 0; nf < NF; ++nf) {
      int lb = lbBase + nf * 16;
      bfv[nf][0] = *(const bf16x8*)&sB[p][lb][cgr0];
      bfv[nf][1] = *(const bf16x8*)&sB[p][lb][cgr1];
    }
    if (pf) {
      stageA(p ^ 1, 0, kt + 1);
      stageB(p ^ 1, kt + 1);
    }
    __builtin_amdgcn_s_setprio(1);
#pragma unroll
    for (int mf = 0; mf < 4; ++mf)
#pragma unroll
      for (int nf = 0; nf < NF; ++nf) {
        acc[mf][nf] = MFMA16(af[mf][0], bfv[nf][0], acc[mf][nf]);
        acc[mf][nf] = MFMA16(af[mf][1], bfv[nf][1], acc[mf][nf]);
      }
    __builtin_amdgcn_s_setprio(0);
    // ======== Ph1: quadrants (1,*). Needs A1 (af overwrite). ========
    if (pf) {
      if constexpr (BN == 256) { VMWAIT(6); } else { VMWAIT(5); }  // lands A1
    } else {
      VMWAIT(0);
    }
    BAR();
#pragma unroll
    for (int mf = 0; mf < 4; ++mf) {
      int la = laBase + mf * 16;
      af[mf][0] = *(const bf16x8*)&sA[p][1][la][cgr0];
      af[mf][1] = *(const bf16x8*)&sA[p][1][la][cgr1];
    }
    if (pf) stageA(p ^ 1, 1, kt + 1);
    __builtin_amdgcn_s_setprio(1);
#pragma unroll
    for (int mf = 0; mf < 4; ++mf)
#pragma unroll
      for (int nf = 0; nf < NF; ++nf) {
        acc[4 + mf][nf] = MFMA16(af[mf][0], bfv[nf][0], acc[4 + mf][nf]);
        acc[4 + mf][nf] = MFMA16(af[mf][1], bfv[nf][1], acc[4 + mf][nf]);
      }
    __builtin_amdgcn_s_setprio(0);
  };

  int p = 0;
  for (int kt = 0; kt < KT - 1; ++kt) {
    ktile(kt, p, true);
    p ^= 1;
  }
  ktile(KT - 1, p, false);  // peeled: no prefetch; waits 2/0

  // ---- epilogue: +bias, optional GELU, bf16 store.
  // C/D mapping (m89): col = lane&15, row = (lane>>4)*4 + r.
  const float* be = bias + (size_t)e * N + bn * BN;
  __hip_bfloat16* oe =
      out + (size_t)e * T_ * N + (size_t)(bm * 256) * N + bn * BN;
  int r4 = l16h * 4;
#pragma unroll
  for (int mi = 0; mi < 8; ++mi) {
    int mh = mi >> 2, mf = mi & 3;
    int rowb = wr * 128 + mh * 64 + mf * 16 + r4;
#pragma unroll
    for (int nf = 0; nf < NF; ++nf) {
      int cc   = wc * WCW + nf * 16 + l15;
      float bv = be[cc];
#pragma unroll
      for (int r = 0; r < 4; ++r) {
        float v = acc[mi][nf][r] + bv;
        if (GELU) v = gelu_fast(v);
        oe[(size_t)(rowb + r) * N + cc] = __float2bfloat16(v);
      }
    }
  }
}

// ---------------------------------------------------------------------------
// Residual + LayerNorm, vectorized (G13): 384 thr/row, each thread owns 2
// cols -> ushort2 loads of yraw and x_bf (residual in bf16: adds <=0.02 abs
// err, margin 0.031 -> ~0.05 vs 0.104 threshold). float2 stores.
// ---------------------------------------------------------------------------
__global__ __launch_bounds__(384) void ln_kernel(
    const __hip_bfloat16* __restrict__ yraw,
    const __hip_bfloat16* __restrict__ xbf,
    const float* __restrict__ gamma, const float* __restrict__ beta,
    float* __restrict__ out) {
  int row  = blockIdx.x;
  int tid  = threadIdx.x;
  int lane = tid & 63, wid = tid >> 6;  // 6 waves
  int c    = tid * 2;
  const __hip_bfloat16* yr = yraw + (size_t)row * H_;
  const __hip_bfloat16* xr = xbf + (size_t)row * H_;

  ushort2 ya = *(const ushort2*)&yr[c];
  ushort2 xa = *(const ushort2*)&xr[c];
  __hip_bfloat16 t;
  float v0, v1;
  *(ushort*)&t = ya.x; v0 = __bfloat162float(t);
  *(ushort*)&t = xa.x; v0 += __bfloat162float(t);
  *(ushort*)&t = ya.y; v1 = __bfloat162float(t);
  *(ushort*)&t = xa.y; v1 += __bfloat162float(t);

  float s = v0 + v1, s2 = v0 * v0 + v1 * v1;
#pragma unroll
  for (int o = 32; o > 0; o >>= 1) {
    s  += __shfl_down(s, o);
    s2 += __shfl_down(s2, o);
  }
  __shared__ float ls[6], ls2[6];
  if (lane == 0) { ls[wid] = s; ls2[wid] = s2; }
  __syncthreads();
  float tot  = ls[0] + ls[1] + ls[2] + ls[3] + ls[4] + ls[5];
  float tot2 = ls2[0] + ls2[1] + ls2[2] + ls2[3] + ls2[4] + ls2[5];
  float mean = tot * (1.0f / 768.0f);
  float var  = tot2 * (1.0f / 768.0f) - mean * mean;
  float inv  = rsqrtf(var + 1e-12f);
  float2 g = *(const float2*)&gamma[c];
  float2 b = *(const float2*)&beta[c];
  float2 o2;
  o2.x = (v0 - mean) * inv * g.x + b.x;
  o2.y = (v1 - mean) * inv * g.y + b.y;
  *(float2*)&out[(size_t)row * H_ + c] = o2;
}

// ---------------------------------------------------------------------------
extern "C" void kernel_launch(void* const* d_in, const int* in_sizes, int n_in,
                              void* d_out, int out_size, void* d_ws,
                              size_t ws_size, hipStream_t stream) {
  const float* x     = (const float*)d_in[0];  // [N, H]
  const float* w1    = (const float*)d_in[1];  // [E, H, I]
  const float* b1    = (const float*)d_in[2];  // [E, I]
  const float* w2    = (const float*)d_in[3];  // [E, I, H]
  const float* b2    = (const float*)d_in[4];  // [E, H]
  const float* gamma = (const float*)d_in[5];  // [H]
  const float* beta  = (const float*)d_in[6];  // [H]
  float* out = (float*)d_out;

  // Workspace layout (192 MiB, exactly full):
  //   w1t  [E][I][H] bf16 @ 0           (37,748,736 B; DEAD after GEMM1 ->
  //                                      yraw [N][H] bf16 aliases @0)
  //   w2t  [E][H][I] bf16 @ 37748736    (37,748,736 B)
  //   x_bf [N][H]    bf16 @ 75497472    (25,165,824 B; live until LN)
  //   inter[E][T][I] bf16 @ 100663296   (100,663,296 B)
  char* ws = (char*)d_ws;
  __hip_bfloat16* w1t   = (__hip_bfloat16*)(ws);
  __hip_bfloat16* w2t   = (__hip_bfloat16*)(ws + 37748736);
  __hip_bfloat16* x_bf  = (__hip_bfloat16*)(ws + 75497472);
  __hip_bfloat16* inter = (__hip_bfloat16*)(ws + 100663296);
  __hip_bfloat16* yraw  = (__hip_bfloat16*)(ws);  // w1t dead after GEMM1

  // fused prep: cvt + w1T + w2T in one launch
  prep_kernel<<<CVT_BLOCKS + 2 * WT_BLOCKS, 256, 0, stream>>>(
      x, x_bf, w1, w1t, w2, w2t);
  // GEMM1 + bias + GELU -> inter : BN=256, 8*8*12 = 768 blocks
  gemm2p_kernel<H_, I_, 256, true>
      <<<E_ * (T_ / 256) * (I_ / 256), 512, 0, stream>>>(x_bf, w1t, b1, inter);
  // GEMM2 + bias -> yraw : BN=192, 8*8*4 = 256 blocks (1 full CU round)
  gemm2p_kernel<I_, H_, 192, false>
      <<<E_ * (T_ / 256) * (H_ / 192), 512, 0, stream>>>(inter, w2t, b2, yraw);
  // residual + LayerNorm -> out (fp32); residual read as bf16 (x_bf)
  ln_kernel<<<NTOK, 384, 0, stream>>>(yraw, x_bf, gamma, beta, out);
}

// Round 10
// 235.474 us; speedup vs baseline: 1.1615x; 1.0128x over previous
//
#include <hip/hip_runtime.h>
#include <hip/hip_bf16.h>
#include <math.h>

// Problem dims (fixed by setup_inputs)
#define E_   8
#define H_   768
#define I_   3072
#define T_   2048
#define NTOK (E_ * T_)

typedef __attribute__((ext_vector_type(8))) short bf16x8;   // 8 bf16 = 4 VGPRs
typedef __attribute__((ext_vector_type(4))) float f32x4;    // MFMA accum

typedef __attribute__((address_space(3))) void lds_void;
typedef const __attribute__((address_space(1))) void gl_void;

__device__ __forceinline__ void gload16(const void* g, void* l) {
  // 16B async global->LDS. LDS dest is wave-uniform base + lane*16.
  __builtin_amdgcn_global_load_lds((gl_void*)g, (lds_void*)l, 16, 0, 0);
}

// Compiler-only fence (0 instructions) + raw HW barrier. NOT __syncthreads():
// that would emit s_waitcnt vmcnt(0) and drain the prefetch pipeline (T4).
#define FENCE() asm volatile("" ::: "memory")
#define BAR()                         \
  do {                                \
    FENCE();                          \
    __builtin_amdgcn_s_barrier();     \
    FENCE();                          \
  } while (0)
#define VMWAIT(n) asm volatile("s_waitcnt vmcnt(" #n ")" ::: "memory")

#define MFMA16(a, b, c) __builtin_amdgcn_mfma_f32_16x16x32_bf16(a, b, c, 0, 0, 0)

// Fast GELU: v * sigmoid(1.5957691*(v + 0.044715 v^3)); |err| ~3e-4 << bf16
// storage error of the intermediate. (Round-2 verified, absmax 0.031.)
__device__ __forceinline__ float gelu_fast(float v) {
  float inner = v * fmaf(v * v, 0.044715f, 1.0f);
  float e = __builtin_amdgcn_exp2f(inner * -2.3022082f);
  return v * __builtin_amdgcn_rcpf(1.0f + e);
}

// ---------------------------------------------------------------------------
// Fused prep kernel (round-9, frozen): one launch does
//   blocks [0, 12288)        : x fp32 -> x_bf bf16 (float4 / ushort4)
//   blocks [12288, 16896)    : w1 [E][H][I] -> w1t [E][I][H] bf16
//   blocks [16896, 21504)    : w2 [E][I][H] -> w2t [E][H][I] bf16
// ---------------------------------------------------------------------------
#define CVT_BLOCKS 12288         // NTOK*H / (256*4)
#define WT_BLOCKS  4608          // (I/64)*(H/64)*E = 48*12*8

__global__ __launch_bounds__(256) void prep_kernel(
    const float* __restrict__ x, __hip_bfloat16* __restrict__ x_bf,
    const float* __restrict__ w1, __hip_bfloat16* __restrict__ w1t,
    const float* __restrict__ w2, __hip_bfloat16* __restrict__ w2t) {
  __shared__ __hip_bfloat16 tile[64][66];
  int b = blockIdx.x;

  if (b < CVT_BLOCKS) {  // ---- cvt branch
    int i = (b * 256 + threadIdx.x) * 4;
    float4 v = *(const float4*)(x + i);
    __align__(8) __hip_bfloat16 t[4];
    t[0] = __float2bfloat16(v.x);
    t[1] = __float2bfloat16(v.y);
    t[2] = __float2bfloat16(v.z);
    t[3] = __float2bfloat16(v.w);
    *(ushort4*)(x_bf + i) = *(const ushort4*)t;
    return;
  }

  // ---- transpose branches: [E][R][C] fp32 -> [E][C][R] bf16
  const float* src;
  __hip_bfloat16* dst;
  int R, C, c0, r0;
  if (b < CVT_BLOCKS + WT_BLOCKS) {
    int t = b - CVT_BLOCKS;
    int e = t / 576, rem = t % 576;       // 576 = (I/64)*(H/64)
    R = H_; C = I_;                       // src w1 [H][I]
    c0 = (rem % 48) * 64;
    r0 = (rem / 48) * 64;
    src = w1 + (size_t)e * R * C;
    dst = w1t + (size_t)e * R * C;
  } else {
    int t = b - (CVT_BLOCKS + WT_BLOCKS);
    int e = t / 576, rem = t % 576;
    R = I_; C = H_;                       // src w2 [I][H]
    c0 = (rem % 12) * 64;
    r0 = (rem / 12) * 64;
    src = w2 + (size_t)e * R * C;
    dst = w2t + (size_t)e * R * C;
  }

  int tx = threadIdx.x & 31;  // col-pair index (2 cols/thread)
  int ty = threadIdx.x >> 5;  // 8 rows/pass
#pragma unroll
  for (int r = ty; r < 64; r += 8) {
    float2 v = *(const float2*)&src[(size_t)(r0 + r) * C + c0 + 2 * tx];
    __hip_bfloat16 b0 = __float2bfloat16(v.x);
    __hip_bfloat16 b1 = __float2bfloat16(v.y);
    ushort2 w;
    w.x = *(const ushort*)&b0;
    w.y = *(const ushort*)&b1;
    *(ushort2*)&tile[r][2 * tx] = w;
  }
  __syncthreads();
#pragma unroll
  for (int rr = ty; rr < 64; rr += 8) {
    ushort2 v;
    v.x = *(const ushort*)&tile[2 * tx][rr];
    v.y = *(const ushort*)&tile[2 * tx + 1][rr];
    *(ushort2*)&dst[(size_t)(c0 + rr) * R + r0 + 2 * tx] = v;
  }
}

// ---------------------------------------------------------------------------
// Grouped GEMM, round-10: 256x192 tile, BK=64, 768 thr = 12 waves (2M x 6N),
// per-wave 128x32 out -> acc = 64 f32/lane, reg budget ~150 ->
// __launch_bounds__(768,3) = 3 waves/SIMD (was 2 at 128x64/wave). +50%
// latency hiding at UNCHANGED per-wave LDS efficiency (12 ds_read_b128 per
// 32 MFMA = 0.375, same as round-5's 24/64) — the round-7 failure mode
// (64x64 waves: 0.5 ratio + 2x fetch) does not apply. LDS 114688 B ->
// 1 block/CU. Grids: GEMM1 8*8*16=1024 (4 clean rounds), GEMM2 8*8*4=256.
//
// 2-phase merged schedule (round-5/8, frozen). Staging: A-halves by waves
// 0-7 only (wave-uniform tid<512; 2 loads/thread/half); B by all 12 waves
// (2 loads/thread). Per-wave-class FIFO vmcnt ledger:
//   class X (waves 0-7): per tile issues A0(2),B(2),A1(2) = 6.
//     Ph0: VMWAIT(2) lands A0,B (1-tile slack). Ph1: VMWAIT(4) lands A1.
//     Peeled: 2 / 0.
//   class Y (waves 8-11): per tile issues B(2) only.
//     Ph0: VMWAIT(0) lands B (issued 1 tile earlier). Ph1: no wait.
// Waits are wave-uniform branches; BAR after wait (visibility via barrier).
// T2 swizzle + T1 XCD swizzle unchanged (bank conflicts measured 0).
// ---------------------------------------------------------------------------
template <int K, int N, bool GELU>
__global__ __launch_bounds__(768, 3) void gemm12w_kernel(
    const __hip_bfloat16* __restrict__ A,
    const __hip_bfloat16* __restrict__ B,
    const float* __restrict__ bias,
    __hip_bfloat16* __restrict__ out) {
  constexpr int BN = 192;
  constexpr int MT = T_ / 256;
  constexpr int NT = N / BN;
  constexpr int KT = K / 64;

  __shared__ __hip_bfloat16 sA[2][2][128][64];  // 65536 B
  __shared__ __hip_bfloat16 sB[2][BN][64];      // 49152 B

  // T1: bijective XCD swizzle (gridDim.x % 8 == 0 for both GEMMs).
  int nwg = gridDim.x;
  int b0  = blockIdx.x;
  int bid = (b0 & 7) * (nwg >> 3) + (b0 >> 3);

  int e   = bid / (MT * NT);
  int rr_ = bid % (MT * NT);
  int bm  = rr_ / NT;
  int bn  = rr_ % NT;

  const __hip_bfloat16* Ae = A + (size_t)e * T_ * K + (size_t)bm * 256 * K;
  const __hip_bfloat16* Be = B + (size_t)e * N  * K + (size_t)bn * BN * K;

  int tid  = threadIdx.x;
  int lane = tid & 63;
  int wid  = tid >> 6;      // 0..11
  int wr   = wid / 6;       // 0..1 (M)
  int wc   = wid % 6;       // 0..5 (N)
  int l15  = lane & 15;
  int l16h = lane >> 4;     // 0..3
  bool isX = (tid < 512);   // wave-uniform staging class

  // --- A staging offsets (valid for class X; 2 loads/thread per half)
  int i0 = tid, i1 = 512 + tid;
  int lr0 = i0 >> 3, c80 = i0 & 7, cg0 = c80 ^ (lr0 & 7);
  int lr1 = i1 >> 3, c81 = i1 & 7, cg1 = c81 ^ (lr1 & 7);
  int rA0 = ((lr0 >> 6) << 7) | (lr0 & 63);  // + h*64 -> global row
  int rA1 = ((lr1 >> 6) << 7) | (lr1 & 63);
  const size_t oA0 = (size_t)rA0 * K + cg0 * 8;
  const size_t oA1 = (size_t)rA1 * K + cg1 * 8;
  const size_t HOFF = (size_t)64 * K;
  // --- B staging offsets (all 12 waves; 2 loads/thread: 1536 = 2*768)
  size_t oB[2];
  int    dB[2];
#pragma unroll
  for (int q = 0; q < 2; ++q) {
    int idx = q * 768 + tid;
    int lr = idx >> 3, c8 = idx & 7;       // lr in [0,192)
    int cg = c8 ^ (lr & 7);
    oB[q] = (size_t)lr * K + cg * 8;
    dB[q] = lr * 64 + c8 * 8;
  }

  auto stageA = [&](int buf, int h, int kt) {
    if (isX) {
      const __hip_bfloat16* g = Ae + (size_t)kt * 64 + (size_t)h * HOFF;
      gload16(g + oA0, &sA[buf][h][lr0][c80 * 8]);
      gload16(g + oA1, &sA[buf][h][lr1][c81 * 8]);
    }
  };
  auto stageB = [&](int buf, int kt) {
    const __hip_bfloat16* g = Be + (size_t)kt * 64;
    __hip_bfloat16* l = &sB[buf][0][0];
    gload16(g + oB[0], l + dB[0]);
    gload16(g + oB[1], l + dB[1]);
  };

  // --- fragment-read geometry (T2 read-side XOR)
  int laBase = wr * 64 + l15;   // + mf*16, within A-half (local rows)
  int lbBase = wc * 32 + l15;   // + nf*16 (rows of sB)
  int s7   = l15 & 7;
  int cgr0 = ((0 | l16h) ^ s7) * 8;  // ks=0 element offset
  int cgr1 = ((4 | l16h) ^ s7) * 8;  // ks=1

  f32x4 acc[8][2] = {};  // [mh*4+mf][nf]
  bf16x8 af[4][2], bfv[2][2];

  // ---- prologue: stage tile 0 in FIFO order A0, B, A1.
  stageA(0, 0, 0);
  stageB(0, 0);
  stageA(0, 1, 0);

  auto ktile = [&](int kt, int p, bool pf) {
    // ======== Ph0: quadrants (0,*). Needs A0 + all B. ========
    if (isX) { VMWAIT(2); } else { VMWAIT(0); }
    BAR();
#pragma unroll
    for (int mf = 0; mf < 4; ++mf) {
      int la = laBase + mf * 16;
      af[mf][0] = *(const bf16x8*)&sA[p][0][la][cgr0];
      af[mf][1] = *(const bf16x8*)&sA[p][0][la][cgr1];
    }
#pragma unroll
    for (int nf = 0; nf < 2; ++nf) {
      int lb = lbBase + nf * 16;
      bfv[nf][0] = *(const bf16x8*)&sB[p][lb][cgr0];
      bfv[nf][1] = *(const bf16x8*)&sB[p][lb][cgr1];
    }
    if (pf) {
      stageA(p ^ 1, 0, kt + 1);
      stageB(p ^ 1, kt + 1);
    }
    __builtin_amdgcn_s_setprio(1);
#pragma unroll
    for (int mf = 0; mf < 4; ++mf)
#pragma unroll
      for (int nf = 0; nf < 2; ++nf) {
        acc[mf][nf] = MFMA16(af[mf][0], bfv[nf][0], acc[mf][nf]);
        acc[mf][nf] = MFMA16(af[mf][1], bfv[nf][1], acc[mf][nf]);
      }
    __builtin_amdgcn_s_setprio(0);
    // ======== Ph1: quadrants (1,*). Needs A1 (af overwrite). ========
    if (pf) {
      if (isX) { VMWAIT(4); }  // lands A1 of kt; Y needs nothing
    } else {
      if (isX) { VMWAIT(0); }
    }
    BAR();
#pragma unroll
    for (int mf = 0; mf < 4; ++mf) {
      int la = laBase + mf * 16;
      af[mf][0] = *(const bf16x8*)&sA[p][1][la][cgr0];
      af[mf][1] = *(const bf16x8*)&sA[p][1][la][cgr1];
    }
    if (pf) stageA(p ^ 1, 1, kt + 1);
    __builtin_amdgcn_s_setprio(1);
#pragma unroll
    for (int mf = 0; mf < 4; ++mf)
#pragma unroll
      for (int nf = 0; nf < 2; ++nf) {
        acc[4 + mf][nf] = MFMA16(af[mf][0], bfv[nf][0], acc[4 + mf][nf]);
        acc[4 + mf][nf] = MFMA16(af[mf][1], bfv[nf][1], acc[4 + mf][nf]);
      }
    __builtin_amdgcn_s_setprio(0);
  };

  int p = 0;
  for (int kt = 0; kt < KT - 1; ++kt) {
    ktile(kt, p, true);
    p ^= 1;
  }
  ktile(KT - 1, p, false);  // peeled: no prefetch

  // ---- epilogue: +bias, optional GELU, bf16 store.
  // C/D mapping (m89): col = lane&15, row = (lane>>4)*4 + r.
  const float* be = bias + (size_t)e * N + bn * BN;
  __hip_bfloat16* oe =
      out + (size_t)e * T_ * N + (size_t)(bm * 256) * N + bn * BN;
  int r4 = l16h * 4;
#pragma unroll
  for (int mi = 0; mi < 8; ++mi) {
    int mh = mi >> 2, mf = mi & 3;
    int rowb = wr * 128 + mh * 64 + mf * 16 + r4;
#pragma unroll
    for (int nf = 0; nf < 2; ++nf) {
      int cc   = wc * 32 + nf * 16 + l15;
      float bv = be[cc];
#pragma unroll
      for (int r = 0; r < 4; ++r) {
        float v = acc[mi][nf][r] + bv;
        if (GELU) v = gelu_fast(v);
        oe[(size_t)(rowb + r) * N + cc] = __float2bfloat16(v);
      }
    }
  }
}

// ---------------------------------------------------------------------------
// Residual + LayerNorm, vectorized (round-8, frozen): 384 thr/row, ushort2
// loads of yraw and x_bf; float2 stores.
// ---------------------------------------------------------------------------
__global__ __launch_bounds__(384) void ln_kernel(
    const __hip_bfloat16* __restrict__ yraw,
    const __hip_bfloat16* __restrict__ xbf,
    const float* __restrict__ gamma, const float* __restrict__ beta,
    float* __restrict__ out) {
  int row  = blockIdx.x;
  int tid  = threadIdx.x;
  int lane = tid & 63, wid = tid >> 6;  // 6 waves
  int c    = tid * 2;
  const __hip_bfloat16* yr = yraw + (size_t)row * H_;
  const __hip_bfloat16* xr = xbf + (size_t)row * H_;

  ushort2 ya = *(const ushort2*)&yr[c];
  ushort2 xa = *(const ushort2*)&xr[c];
  __hip_bfloat16 t;
  float v0, v1;
  *(ushort*)&t = ya.x; v0 = __bfloat162float(t);
  *(ushort*)&t = xa.x; v0 += __bfloat162float(t);
  *(ushort*)&t = ya.y; v1 = __bfloat162float(t);
  *(ushort*)&t = xa.y; v1 += __bfloat162float(t);

  float s = v0 + v1, s2 = v0 * v0 + v1 * v1;
#pragma unroll
  for (int o = 32; o > 0; o >>= 1) {
    s  += __shfl_down(s, o);
    s2 += __shfl_down(s2, o);
  }
  __shared__ float ls[6], ls2[6];
  if (lane == 0) { ls[wid] = s; ls2[wid] = s2; }
  __syncthreads();
  float tot  = ls[0] + ls[1] + ls[2] + ls[3] + ls[4] + ls[5];
  float tot2 = ls2[0] + ls2[1] + ls2[2] + ls2[3] + ls2[4] + ls2[5];
  float mean = tot * (1.0f / 768.0f);
  float var  = tot2 * (1.0f / 768.0f) - mean * mean;
  float inv  = rsqrtf(var + 1e-12f);
  float2 g = *(const float2*)&gamma[c];
  float2 b = *(const float2*)&beta[c];
  float2 o2;
  o2.x = (v0 - mean) * inv * g.x + b.x;
  o2.y = (v1 - mean) * inv * g.y + b.y;
  *(float2*)&out[(size_t)row * H_ + c] = o2;
}

// ---------------------------------------------------------------------------
extern "C" void kernel_launch(void* const* d_in, const int* in_sizes, int n_in,
                              void* d_out, int out_size, void* d_ws,
                              size_t ws_size, hipStream_t stream) {
  const float* x     = (const float*)d_in[0];  // [N, H]
  const float* w1    = (const float*)d_in[1];  // [E, H, I]
  const float* b1    = (const float*)d_in[2];  // [E, I]
  const float* w2    = (const float*)d_in[3];  // [E, I, H]
  const float* b2    = (const float*)d_in[4];  // [E, H]
  const float* gamma = (const float*)d_in[5];  // [H]
  const float* beta  = (const float*)d_in[6];  // [H]
  float* out = (float*)d_out;

  // Workspace layout (192 MiB, exactly full):
  //   w1t  [E][I][H] bf16 @ 0           (37,748,736 B; DEAD after GEMM1 ->
  //                                      yraw [N][H] bf16 aliases @0)
  //   w2t  [E][H][I] bf16 @ 37748736    (37,748,736 B)
  //   x_bf [N][H]    bf16 @ 75497472    (25,165,824 B; live until LN)
  //   inter[E][T][I] bf16 @ 100663296   (100,663,296 B)
  char* ws = (char*)d_ws;
  __hip_bfloat16* w1t   = (__hip_bfloat16*)(ws);
  __hip_bfloat16* w2t   = (__hip_bfloat16*)(ws + 37748736);
  __hip_bfloat16* x_bf  = (__hip_bfloat16*)(ws + 75497472);
  __hip_bfloat16* inter = (__hip_bfloat16*)(ws + 100663296);
  __hip_bfloat16* yraw  = (__hip_bfloat16*)(ws);  // w1t dead after GEMM1

  // fused prep: cvt + w1T + w2T in one launch
  prep_kernel<<<CVT_BLOCKS + 2 * WT_BLOCKS, 256, 0, stream>>>(
      x, x_bf, w1, w1t, w2, w2t);
  // GEMM1 + bias + GELU -> inter : BN=192, 8*8*16 = 1024 blocks (4 rounds)
  gemm12w_kernel<H_, I_, true>
      <<<E_ * (T_ / 256) * (I_ / 192), 768, 0, stream>>>(x_bf, w1t, b1, inter);
  // GEMM2 + bias -> yraw : BN=192, 8*8*4 = 256 blocks (1 full round)
  gemm12w_kernel<I_, H_, false>
      <<<E_ * (T_ / 256) * (H_ / 192), 768, 0, stream>>>(inter, w2t, b2, yraw);
  // residual + LayerNorm -> out (fp32); residual read as bf16 (x_bf)
  ln_kernel<<<NTOK, 384, 0, stream>>>(yraw, x_bf, gamma, beta, out);
}